// Round 11
// baseline (710.826 us; speedup 1.0000x reference)
//
#include <hip/hip_runtime.h>
#include <stdint.h>
#include <stddef.h>

#define N_ATOMS 50000
#define N_EDGES 524288
#define FA 133
#define FB 14
#define H 128
#define DEPTH 3
#define KI 160   /* 133 padded to multiple of 32 */
#define KB 32    /* 14 padded to 32 */
#define KR 128
#define SCAN_NB 98   /* ceil(50000/512) */

typedef __attribute__((ext_vector_type(8))) __bf16 bf16x8;
typedef __attribute__((ext_vector_type(4))) float f32x4;

__device__ __forceinline__ uint16_t f2bf(float f) {
    uint32_t u = __builtin_bit_cast(uint32_t, f);
    return (uint16_t)((u + 0x7FFFu + ((u >> 16) & 1u)) >> 16);
}
__device__ __forceinline__ float bf2f(uint16_t h) {
    return __builtin_bit_cast(float, (uint32_t)h << 16);
}
__device__ __forceinline__ uint32_t pack2(float a, float b) {
#if __has_builtin(__builtin_amdgcn_cvt_pk_bf16_f32)
    typedef __attribute__((ext_vector_type(2))) __bf16 bf16x2_t;
    bf16x2_t v = __builtin_amdgcn_cvt_pk_bf16_f32(a, b);
    return __builtin_bit_cast(uint32_t, v);
#else
    return (uint32_t)f2bf(a) | ((uint32_t)f2bf(b) << 16);
#endif
}

// async 16B global -> LDS (dest = wave-uniform base + lane*16)
__device__ __forceinline__ void async_load16(const uint16_t* g, uint16_t* l) {
    __builtin_amdgcn_global_load_lds(
        (const __attribute__((address_space(1))) uint32_t*)(const void*)g,
        (__attribute__((address_space(3))) uint32_t*)(void*)l,
        16, 0, 0);
}

// ---- weight conversion ----------------------------------------------------
__global__ void k_weights(const float* __restrict__ Wi_f,
                          const float* __restrict__ Wu_f,
                          const float* __restrict__ Wr_f,
                          uint16_t* __restrict__ Wa,
                          uint16_t* __restrict__ Wb,
                          uint16_t* __restrict__ Wu0,
                          uint16_t* __restrict__ Wu1,
                          uint16_t* __restrict__ Wu1n,
                          uint16_t* __restrict__ Wr) {
    const int O0 = H * KI, O1 = O0 + H * KB, O2 = O1 + H * 128,
              O3 = O2 + H * 128, O4 = O3 + H * 128, O5 = O4 + H * KR;
    int i = blockIdx.x * 256 + threadIdx.x;
    if (i < O0) {
        int o = i / KI, k = i - o * KI;
        Wa[i] = f2bf((k < FA) ? Wi_f[o * (FA + FB) + k] : 0.f);
    } else if (i < O1) {
        int j = i - O0;
        int o = j >> 5, k = j & 31;
        Wb[j] = f2bf((k < FB) ? Wi_f[o * (FA + FB) + FA + k] : 0.f);
    } else if (i < O2) {
        int j = i - O1;
        int o = j >> 7, k = j & 127;
        Wu0[j] = f2bf(Wu_f[o * 256 + k]);
    } else if (i < O3) {
        int j = i - O2;
        int o = j >> 7, k = j & 127;
        Wu1[j] = f2bf(Wu_f[o * 256 + 128 + k]);
    } else if (i < O4) {
        int j = i - O3;
        int o = j >> 7, k = j & 127;
        Wu1n[j] = f2bf(-Wu_f[o * 256 + 128 + k]);
    } else if (i < O5) {
        int j = i - O4;
        Wr[j] = f2bf(Wr_f[j]);
    }
}

// ---------------- CSR build ------------------------------------------------
__global__ void k_hist(const int* __restrict__ dstv, int* __restrict__ counts) {
    int e = blockIdx.x * 256 + threadIdx.x;
    if (e < N_EDGES) atomicAdd(&counts[dstv[e]], 1);
}

__global__ void k_scan1(const int* __restrict__ counts,
                        int* __restrict__ lscan, int* __restrict__ partials) {
    __shared__ int s[512];
    const int t = threadIdx.x, b = blockIdx.x;
    const int i = b * 512 + t;
    const int c = (i < N_ATOMS) ? counts[i] : 0;
    s[t] = c;
    __syncthreads();
    for (int off = 1; off < 512; off <<= 1) {
        int u = (t >= off) ? s[t - off] : 0;
        __syncthreads();
        s[t] += u;
        __syncthreads();
    }
    lscan[i] = s[t] - c;  // exclusive
    if (t == 511) partials[b] = s[511];
}

__global__ void k_scan2(const int* __restrict__ partials, int* __restrict__ poff) {
    __shared__ int s[128];
    const int t = threadIdx.x;
    const int v = (t < SCAN_NB) ? partials[t] : 0;
    s[t] = v;
    __syncthreads();
    for (int off = 1; off < 128; off <<= 1) {
        int u = (t >= off) ? s[t - off] : 0;
        __syncthreads();
        s[t] += u;
        __syncthreads();
    }
    poff[t] = s[t] - v;  // exclusive
}

__global__ void k_scan3(const int* __restrict__ lscan, const int* __restrict__ poff,
                        int* __restrict__ row_ptr, int* __restrict__ nxt) {
    const int i = blockIdx.x * 512 + threadIdx.x;
    if (i < N_ATOMS) {
        const int v = poff[blockIdx.x] + lscan[i];
        row_ptr[i] = v;
        nxt[i] = v;
    }
    if (i == 0) row_ptr[N_ATOMS] = N_EDGES;
}

__global__ void k_scatter(const int* __restrict__ dstv, int* __restrict__ nxt,
                          int* __restrict__ edge_slot) {
    int e = blockIdx.x * 256 + threadIdx.x;
    if (e < N_EDGES) {
        int pos = atomicAdd(&nxt[dstv[e]], 1);
        edge_slot[pos] = e;
    }
}

// ---- P = atom @ Wa^T (dense, gather-free) ---------------------------------
__global__ __launch_bounds__(256, 3) void k_atom_gemm(
    const float* __restrict__ atom, const uint16_t* __restrict__ Wa,
    uint16_t* __restrict__ P) {
    __shared__ __align__(16) uint16_t A[128 * 168];
    const int t = threadIdx.x;
    const int base = blockIdx.x * 128;
    if (t < 128) {
        for (int c = FA; c < KI; ++c) A[t * 168 + c] = 0;
    }
    for (int j = 0; j < 67; ++j) {
        int f = j * 256 + t;
        if (f < 128 * FA) {
            int row = f / FA, col = f - row * FA;
            int a = base + row;
            float v = (a < N_ATOMS) ? atom[(size_t)a * FA + col] : 0.f;
            A[row * 168 + col] = f2bf(v);
        }
    }
    __syncthreads();
    const int w = t >> 6, lane = t & 63;
    const int wm = w >> 1, wn = w & 1;
    const int l15 = lane & 15, q = lane >> 4;
    f32x4 acc[4][4];
    const f32x4 z = {0.f, 0.f, 0.f, 0.f};
    for (int i = 0; i < 4; ++i)
        for (int jj = 0; jj < 4; ++jj) acc[i][jj] = z;
#pragma unroll
    for (int ks = 0; ks < 5; ++ks) {
        const int kk = ks * 32 + q * 8;
        bf16x8 a[4], b[4];
#pragma unroll
        for (int i = 0; i < 4; ++i)
            a[i] = *(const bf16x8*)&A[(wm * 64 + i * 16 + l15) * 168 + kk];
#pragma unroll
        for (int jj = 0; jj < 4; ++jj)
            b[jj] = *(const bf16x8*)&Wa[(wn * 64 + jj * 16 + l15) * KI + kk];
#pragma unroll
        for (int i = 0; i < 4; ++i)
#pragma unroll
            for (int jj = 0; jj < 4; ++jj)
                acc[i][jj] = __builtin_amdgcn_mfma_f32_16x16x32_bf16(a[i], b[jj], acc[i][jj], 0, 0, 0);
    }
    __syncthreads();
#pragma unroll
    for (int jj = 0; jj < 4; ++jj) {
        const int col = wn * 64 + jj * 16 + l15;
#pragma unroll
        for (int i = 0; i < 4; ++i)
#pragma unroll
            for (int r = 0; r < 4; ++r) {
                const int row = wm * 64 + i * 16 + q * 4 + r;
                A[row * 136 + col] = f2bf(acc[i][jj][r]);
            }
    }
    __syncthreads();
    for (int j = 0; j < 8; ++j) {
        int c = j * 256 + t;
        int row = c >> 4, kc = c & 15;
        *(bf16x8*)(P + (size_t)(base + row) * H + kc * 8) =
            *(const bf16x8*)&A[row * 136 + kc * 8];
    }
}

// ---- h0 = relu(P[src] + bond @ Wb^T + b_init) -----------------------------
__global__ __launch_bounds__(512, 2) void k_edge_init(
    const float* __restrict__ bond, const int* __restrict__ srcv,
    const uint16_t* __restrict__ Wb, const uint16_t* __restrict__ P,
    const float* __restrict__ b_init, uint16_t* __restrict__ h_out) {
    __shared__ __align__(16) uint16_t Pl[128 * 128];  // async gathered P rows
    __shared__ __align__(16) uint16_t Pk[128 * 136];  // acc park (+8 pad)
    __shared__ __align__(16) uint16_t Bb[128 * 40];   // bond bf16 (cols 0..31)
    __shared__ float bias_lds[128];
    const int t = threadIdx.x;
    const int base = blockIdx.x * 128;
    const int w = t >> 6, lane = t & 63;
    if (t < 128) bias_lds[t] = b_init[t];
#pragma unroll
    for (int j = 0; j < 4; ++j) {
        const int task = j * 512 + t;
        const int row = task >> 4, sp = task & 15;
        const int wavebase = j * 512 + w * 64;
        const int s = srcv[base + row];
        async_load16(P + (size_t)s * H + sp * 8, Pl + wavebase * 8);
    }
#pragma unroll
    for (int j = 0; j < 8; ++j) {
        const int task = j * 512 + t;
        const int row = task >> 5, col = task & 31;
        float v = (col < FB) ? bond[(size_t)(base + row) * FB + col] : 0.f;
        Bb[row * 40 + col] = f2bf(v);
    }
    __syncthreads();  // Pl drain + Bb visible
    const int wm = w >> 2, wn = w & 3;
    const int l15 = lane & 15, q = lane >> 4;
    f32x4 acc[4][2];
    const f32x4 z = {0.f, 0.f, 0.f, 0.f};
    for (int i = 0; i < 4; ++i)
        for (int jj = 0; jj < 2; ++jj) acc[i][jj] = z;
    {
        bf16x8 a[4], b[2];
#pragma unroll
        for (int i = 0; i < 4; ++i)
            a[i] = *(const bf16x8*)&Bb[(wm * 64 + i * 16 + l15) * 40 + q * 8];
#pragma unroll
        for (int jj = 0; jj < 2; ++jj)
            b[jj] = *(const bf16x8*)&Wb[(wn * 32 + jj * 16 + l15) * KB + q * 8];
#pragma unroll
        for (int i = 0; i < 4; ++i)
#pragma unroll
            for (int jj = 0; jj < 2; ++jj)
                acc[i][jj] = __builtin_amdgcn_mfma_f32_16x16x32_bf16(a[i], b[jj], acc[i][jj], 0, 0, 0);
    }
#pragma unroll
    for (int jj = 0; jj < 2; ++jj) {
        const int col = wn * 32 + jj * 16 + l15;
#pragma unroll
        for (int i = 0; i < 4; ++i)
#pragma unroll
            for (int r = 0; r < 4; ++r) {
                const int row = wm * 64 + i * 16 + q * 4 + r;
                Pk[row * 136 + col] = f2bf(acc[i][jj][r]);
            }
    }
    __syncthreads();
#pragma unroll
    for (int j = 0; j < 4; ++j) {
        const int task = j * 512 + t;
        const int row = task >> 4, sl = task & 15;
        const bf16x8 a8 = *(const bf16x8*)&Pk[row * 136 + sl * 8];
        const bf16x8 p8 = *(const bf16x8*)&Pl[row * 128 + sl * 8];
        uint4 pck;
        uint32_t parts[4];
#pragma unroll
        for (int hw = 0; hw < 4; ++hw) {
            float v0 = (float)a8[hw * 2] + (float)p8[hw * 2] + bias_lds[sl * 8 + hw * 2];
            float v1 = (float)a8[hw * 2 + 1] + (float)p8[hw * 2 + 1] + bias_lds[sl * 8 + hw * 2 + 1];
            v0 = v0 > 0.f ? v0 : 0.f;
            v1 = v1 > 0.f ? v1 : 0.f;
            parts[hw] = pack2(v0, v1);
        }
        pck.x = parts[0]; pck.y = parts[1]; pck.z = parts[2]; pck.w = parts[3];
        *(uint4*)(h_out + (size_t)(base + row) * H + sl * 8) = pck;
    }
}

// ---- streamed segsum into LDS tile S --------------------------------------
// Quarter-wave owns 8 atoms whose CSR slot ranges are CONTIGUOUS; stream the
// whole range with a 4-deep pipeline that never drains, flushing acc to S at
// row_ptr boundaries (uniform across the 16 lanes). R10's 8-deep per-atom
// pipeline regressed (reg pressure); R9's 4-deep restarted 8x per quarter.
__device__ __forceinline__ void segsum_stream(
    const uint16_t* __restrict__ h, const int* __restrict__ row_ptr,
    const int* __restrict__ edge_slot, uint16_t* __restrict__ S,
    int base, int qw, int ql) {
    const int a0 = base + qw * 8;
    int b[9];
#pragma unroll
    for (int i = 0; i <= 8; ++i) {
        int a = a0 + i;
        b[i] = row_ptr[a > N_ATOMS ? N_ATOMS : a];
    }
    float acc[8];
#pragma unroll
    for (int k = 0; k < 8; ++k) acc[k] = 0.f;
    int cur = 0;
    int p = b[0];
    const int end = b[8];
    int e[4];
#pragma unroll
    for (int i = 0; i < 4; ++i) e[i] = (p + i < end) ? edge_slot[p + i] : 0;
    while (p < end) {
        bf16x8 v[4];
        bool has[4];
#pragma unroll
        for (int i = 0; i < 4; ++i) {
            has[i] = (p + i < end);
            if (has[i]) v[i] = *(const bf16x8*)(h + (size_t)e[i] * H + ql * 8);
        }
#pragma unroll
        for (int i = 0; i < 4; ++i) {
            int np = p + 4 + i;
            e[i] = (np < end) ? edge_slot[np] : 0;
        }
#pragma unroll
        for (int i = 0; i < 4; ++i) {
            if (has[i]) {
                while (p + i >= b[cur + 1]) {  // flush finished atoms
                    uint4 o;
                    o.x = pack2(acc[0], acc[1]);
                    o.y = pack2(acc[2], acc[3]);
                    o.z = pack2(acc[4], acc[5]);
                    o.w = pack2(acc[6], acc[7]);
                    *(uint4*)&S[(qw * 8 + cur) * 136 + ql * 8] = o;
#pragma unroll
                    for (int k = 0; k < 8; ++k) acc[k] = 0.f;
                    ++cur;
                }
#pragma unroll
                for (int k = 0; k < 8; ++k) acc[k] += (float)v[i][k];
            }
        }
        p += 4;
    }
    while (cur < 8) {  // flush remaining (incl. tail + degree-0 atoms)
        uint4 o;
        o.x = pack2(acc[0], acc[1]);
        o.y = pack2(acc[2], acc[3]);
        o.z = pack2(acc[4], acc[5]);
        o.w = pack2(acc[6], acc[7]);
        *(uint4*)&S[(qw * 8 + cur) * 136 + ql * 8] = o;
#pragma unroll
        for (int k = 0; k < 8; ++k) acc[k] = 0.f;
        ++cur;
    }
}

// ---- FUSED segsum + G GEMM: G[a] = (sum_{dst==a} h) @ Wu1^T + b_upd -------
// (bias folded into G: each edge gathers G[src] exactly once in k_update)
__global__ __launch_bounds__(256, 4) void k_sg(
    const uint16_t* __restrict__ h, const int* __restrict__ row_ptr,
    const int* __restrict__ edge_slot, const uint16_t* __restrict__ Wu1,
    const float* __restrict__ b_upd, uint16_t* __restrict__ G) {
    __shared__ __align__(16) uint16_t S[128 * 136];
    const int t = threadIdx.x;
    const int base = blockIdx.x * 128;
    const int qw = t >> 4, ql = t & 15;
    segsum_stream(h, row_ptr, edge_slot, S, base, qw, ql);
    __syncthreads();
    const int w = t >> 6, lane = t & 63;
    const int wm = w >> 1, wn = w & 1;
    const int l15 = lane & 15, q = lane >> 4;
    f32x4 acc[4][4];
    const f32x4 z = {0.f, 0.f, 0.f, 0.f};
    for (int i = 0; i < 4; ++i)
        for (int jj = 0; jj < 4; ++jj) acc[i][jj] = z;
#pragma unroll
    for (int ks = 0; ks < 4; ++ks) {
        const int kk = ks * 32 + q * 8;
        bf16x8 a[4], b[4];
#pragma unroll
        for (int i = 0; i < 4; ++i)
            a[i] = *(const bf16x8*)&S[(wm * 64 + i * 16 + l15) * 136 + kk];
#pragma unroll
        for (int jj = 0; jj < 4; ++jj)
            b[jj] = *(const bf16x8*)&Wu1[(wn * 64 + jj * 16 + l15) * 128 + kk];
#pragma unroll
        for (int i = 0; i < 4; ++i)
#pragma unroll
            for (int jj = 0; jj < 4; ++jj)
                acc[i][jj] = __builtin_amdgcn_mfma_f32_16x16x32_bf16(a[i], b[jj], acc[i][jj], 0, 0, 0);
    }
    __syncthreads();
#pragma unroll
    for (int jj = 0; jj < 4; ++jj) {
        const int col = wn * 64 + jj * 16 + l15;
        const float bias = b_upd[col];
#pragma unroll
        for (int i = 0; i < 4; ++i)
#pragma unroll
            for (int r = 0; r < 4; ++r) {
                const int row = wm * 64 + i * 16 + q * 4 + r;
                S[row * 136 + col] = f2bf(acc[i][jj][r] + bias);
            }
    }
    __syncthreads();
    for (int j = 0; j < 8; ++j) {
        int c = j * 256 + t;
        int row = c >> 4, kc = c & 15;
        int a_idx = base + row;
        if (a_idx < N_ATOMS)
            *(bf16x8*)(G + (size_t)a_idx * H + kc * 8) =
                *(const bf16x8*)&S[row * 136 + kc * 8];
    }
}

// ---- update: h' = relu(h@Wu0^T + h[e^1]@(-Wu1)^T + G[src]) ----------------
// (G carries the bias). Async staging of h tile + G gather; one drain.
__global__ __launch_bounds__(512, 2) void k_update(
    uint16_t* __restrict__ h_io, const uint16_t* __restrict__ G,
    const int* __restrict__ srcv, const uint16_t* __restrict__ Wu0,
    const uint16_t* __restrict__ Wu1n) {
    __shared__ __align__(16) uint16_t A[128 * 128];   // swizzled h tile / acc park
    __shared__ __align__(16) uint16_t Gl[128 * 128];  // gathered G rows
    const int t = threadIdx.x;
    const int base = blockIdx.x * 128;
    const int w = t >> 6, lane = t & 63;
#pragma unroll
    for (int j = 0; j < 4; ++j) {
        const int task = j * 512 + t;
        const int row = task >> 4, sp = task & 15;
        const int sl = sp ^ (row & 15);
        const int wavebase = j * 512 + w * 64;  // uniform per wave
        async_load16(h_io + (size_t)(base + row) * H + sl * 8, A + wavebase * 8);
        const int s = srcv[base + row];
        async_load16(G + (size_t)s * H + sp * 8, Gl + wavebase * 8);
    }
    __syncthreads();  // single drain: h + G land together
    const int wm = w >> 2, wn = w & 3;
    const int l15 = lane & 15, q = lane >> 4;
    const int l15r = l15 ^ 1;
    f32x4 acc[4][2];
    const f32x4 z = {0.f, 0.f, 0.f, 0.f};
    for (int i = 0; i < 4; ++i)
        for (int jj = 0; jj < 2; ++jj) acc[i][jj] = z;
#pragma unroll
    for (int ks = 0; ks < 4; ++ks) {
        const int ck = ks * 4 + q;
        const int kk = ck * 8;
        bf16x8 a[4], b[2];
#pragma unroll
        for (int i = 0; i < 4; ++i)
            a[i] = *(const bf16x8*)&A[(wm * 64 + i * 16 + l15) * 128 + (ck ^ l15) * 8];
#pragma unroll
        for (int jj = 0; jj < 2; ++jj)
            b[jj] = *(const bf16x8*)&Wu0[(wn * 32 + jj * 16 + l15) * 128 + kk];
#pragma unroll
        for (int i = 0; i < 4; ++i)
#pragma unroll
            for (int jj = 0; jj < 2; ++jj)
                acc[i][jj] = __builtin_amdgcn_mfma_f32_16x16x32_bf16(a[i], b[jj], acc[i][jj], 0, 0, 0);
    }
#pragma unroll
    for (int ks = 0; ks < 4; ++ks) {
        const int ck = ks * 4 + q;
        const int kk = ck * 8;
        bf16x8 a[4], b[2];
#pragma unroll
        for (int i = 0; i < 4; ++i)
            a[i] = *(const bf16x8*)&A[(wm * 64 + i * 16 + l15r) * 128 + (ck ^ l15r) * 8];
#pragma unroll
        for (int jj = 0; jj < 2; ++jj)
            b[jj] = *(const bf16x8*)&Wu1n[(wn * 32 + jj * 16 + l15) * 128 + kk];
#pragma unroll
        for (int i = 0; i < 4; ++i)
#pragma unroll
            for (int jj = 0; jj < 2; ++jj)
                acc[i][jj] = __builtin_amdgcn_mfma_f32_16x16x32_bf16(a[i], b[jj], acc[i][jj], 0, 0, 0);
    }
    __syncthreads();  // all A reads done
#pragma unroll
    for (int jj = 0; jj < 2; ++jj) {
        const int col = wn * 32 + jj * 16 + l15;
        const int cc = col >> 3, c7 = col & 7;
#pragma unroll
        for (int i = 0; i < 4; ++i)
#pragma unroll
            for (int r = 0; r < 4; ++r) {
                const int row = wm * 64 + i * 16 + q * 4 + r;
                A[row * 128 + (cc ^ (row & 15)) * 8 + c7] = f2bf(acc[i][jj][r]);
            }
    }
    __syncthreads();
#pragma unroll
    for (int j = 0; j < 4; ++j) {
        const int task = j * 512 + t;
        const int row = task >> 4, sl = task & 15;
        const bf16x8 a8 = *(const bf16x8*)&A[row * 128 + (sl ^ (row & 15)) * 8];
        const bf16x8 g8 = *(const bf16x8*)&Gl[row * 128 + sl * 8];
        uint4 pck;
        uint32_t parts[4];
#pragma unroll
        for (int hw = 0; hw < 4; ++hw) {
            float v0 = (float)a8[hw * 2] + (float)g8[hw * 2];
            float v1 = (float)a8[hw * 2 + 1] + (float)g8[hw * 2 + 1];
            v0 = v0 > 0.f ? v0 : 0.f;
            v1 = v1 > 0.f ? v1 : 0.f;
            parts[hw] = pack2(v0, v1);
        }
        pck.x = parts[0]; pck.y = parts[1]; pck.z = parts[2]; pck.w = parts[3];
        *(uint4*)(h_io + (size_t)(base + row) * H + sl * 8) = pck;
    }
}

// ---- FUSED final segsum + readout: out += colsum(relu(sum @ Wr^T + b)) ----
__global__ __launch_bounds__(256, 4) void k_sr(
    const uint16_t* __restrict__ h, const int* __restrict__ row_ptr,
    const int* __restrict__ edge_slot, const uint16_t* __restrict__ Wr,
    const float* __restrict__ b_read, float* __restrict__ out) {
    __shared__ __align__(16) uint16_t S[128 * 136];
    __shared__ float col_lds[128];
    const int t = threadIdx.x;
    const int base = blockIdx.x * 128;
    const int qw = t >> 4, ql = t & 15;
    if (t < 128) col_lds[t] = 0.f;
    segsum_stream(h, row_ptr, edge_slot, S, base, qw, ql);
    __syncthreads();
    const int w = t >> 6, lane = t & 63;
    const int wm = w >> 1, wn = w & 1;
    const int l15 = lane & 15, q = lane >> 4;
    f32x4 acc[4][4];
    const f32x4 z = {0.f, 0.f, 0.f, 0.f};
    for (int i = 0; i < 4; ++i)
        for (int jj = 0; jj < 4; ++jj) acc[i][jj] = z;
#pragma unroll
    for (int ks = 0; ks < 4; ++ks) {
        const int kk = ks * 32 + q * 8;
        bf16x8 a[4], b[4];
#pragma unroll
        for (int i = 0; i < 4; ++i)
            a[i] = *(const bf16x8*)&S[(wm * 64 + i * 16 + l15) * 136 + kk];
#pragma unroll
        for (int jj = 0; jj < 4; ++jj)
            b[jj] = *(const bf16x8*)&Wr[(wn * 64 + jj * 16 + l15) * KR + kk];
#pragma unroll
        for (int i = 0; i < 4; ++i)
#pragma unroll
            for (int jj = 0; jj < 4; ++jj)
                acc[i][jj] = __builtin_amdgcn_mfma_f32_16x16x32_bf16(a[i], b[jj], acc[i][jj], 0, 0, 0);
    }
#pragma unroll
    for (int jj = 0; jj < 4; ++jj) {
        const int col = wn * 64 + jj * 16 + l15;
        const float bias = b_read[col];
        float s = 0.f;
#pragma unroll
        for (int i = 0; i < 4; ++i)
#pragma unroll
            for (int r = 0; r < 4; ++r) {
                const int a_idx = base + wm * 64 + i * 16 + q * 4 + r;
                if (a_idx < N_ATOMS) {
                    float v = acc[i][jj][r] + bias;
                    s += (v > 0.f) ? v : 0.f;
                }
            }
        atomicAdd(&col_lds[col], s);
    }
    __syncthreads();
    if (t < 128) atomicAdd(&out[t], col_lds[t]);
}

// ---------------- launch ---------------------------------------------------
extern "C" void kernel_launch(void* const* d_in, const int* in_sizes, int n_in,
                              void* d_out, int out_size, void* d_ws, size_t ws_size,
                              hipStream_t stream) {
    (void)in_sizes; (void)n_in; (void)out_size; (void)ws_size;
    const float* atom   = (const float*)d_in[0];
    const float* bond   = (const float*)d_in[1];
    const int* edge_idx = (const int*)d_in[2];
    const float* W_init = (const float*)d_in[3];
    const float* b_init = (const float*)d_in[4];
    const float* W_upd  = (const float*)d_in[5];
    const float* b_upd  = (const float*)d_in[6];
    const float* W_read = (const float*)d_in[7];
    const float* b_read = (const float*)d_in[8];
    float* out = (float*)d_out;

    char* ws = (char*)d_ws;
    constexpr size_t SZ_H    = (size_t)N_EDGES * H * 2;            // 134217728
    constexpr size_t OFF_H   = 0;
    constexpr size_t OFF_P   = OFF_H + SZ_H;
    constexpr size_t OFF_G   = OFF_P + (size_t)N_ATOMS * H * 2;
    constexpr size_t OFF_WA  = OFF_G + (size_t)N_ATOMS * H * 2;
    constexpr size_t OFF_WB  = OFF_WA + (size_t)H * KI * 2;
    constexpr size_t OFF_WU0 = OFF_WB + (size_t)H * KB * 2;
    constexpr size_t OFF_WU1 = OFF_WU0 + (size_t)H * 128 * 2;
    constexpr size_t OFF_WU1N= OFF_WU1 + (size_t)H * 128 * 2;
    constexpr size_t OFF_WR  = OFF_WU1N + (size_t)H * 128 * 2;
    constexpr size_t OFF_CNT = OFF_WR + (size_t)H * KR * 2;
    constexpr size_t OFF_RP  = OFF_CNT + 200192;
    constexpr size_t OFF_NXT = OFF_RP + 200704;
    constexpr size_t OFF_ES  = OFF_NXT + 200192;
    constexpr size_t OFF_LS  = OFF_ES + (size_t)N_EDGES * 4;
    constexpr size_t OFF_PT  = OFF_LS + 512 * SCAN_NB * 4;
    constexpr size_t OFF_PO  = OFF_PT + 512;

    uint16_t* h     = (uint16_t*)(ws + OFF_H);
    uint16_t* P     = (uint16_t*)(ws + OFF_P);
    uint16_t* G     = (uint16_t*)(ws + OFF_G);
    uint16_t* Wa    = (uint16_t*)(ws + OFF_WA);
    uint16_t* Wb    = (uint16_t*)(ws + OFF_WB);
    uint16_t* Wu0   = (uint16_t*)(ws + OFF_WU0);
    uint16_t* Wu1   = (uint16_t*)(ws + OFF_WU1);
    uint16_t* Wu1n  = (uint16_t*)(ws + OFF_WU1N);
    uint16_t* Wr    = (uint16_t*)(ws + OFF_WR);
    int* counts     = (int*)(ws + OFF_CNT);
    int* row_ptr    = (int*)(ws + OFF_RP);
    int* nxt        = (int*)(ws + OFF_NXT);
    int* edge_slot  = (int*)(ws + OFF_ES);
    int* lscan      = (int*)(ws + OFF_LS);
    int* partials   = (int*)(ws + OFF_PT);
    int* poff       = (int*)(ws + OFF_PO);

    const int* srcv = edge_idx;
    const int* dstv = edge_idx + N_EDGES;

    hipMemsetAsync(counts, 0, N_ATOMS * sizeof(int), stream);
    hipMemsetAsync(d_out, 0, H * sizeof(float), stream);

    const int NW = H * KI + H * KB + 3 * H * 128 + H * KR;  // 90112
    k_weights<<<(NW + 255) / 256, 256, 0, stream>>>(
        W_init, W_upd, W_read, Wa, Wb, Wu0, Wu1, Wu1n, Wr);
    k_hist<<<(N_EDGES + 255) / 256, 256, 0, stream>>>(dstv, counts);
    k_scan1<<<SCAN_NB, 512, 0, stream>>>(counts, lscan, partials);
    k_scan2<<<1, 128, 0, stream>>>(partials, poff);
    k_scan3<<<SCAN_NB, 512, 0, stream>>>(lscan, poff, row_ptr, nxt);
    k_scatter<<<(N_EDGES + 255) / 256, 256, 0, stream>>>(dstv, nxt, edge_slot);

    k_atom_gemm<<<(N_ATOMS + 127) / 128, 256, 0, stream>>>(atom, Wa, P);
    k_edge_init<<<N_EDGES / 128, 512, 0, stream>>>(bond, srcv, Wb, P, b_init, h);

    for (int d = 0; d < DEPTH; ++d) {
        k_sg<<<(N_ATOMS + 127) / 128, 256, 0, stream>>>(h, row_ptr, edge_slot, Wu1, b_upd, G);
        k_update<<<N_EDGES / 128, 512, 0, stream>>>(h, G, srcv, Wu0, Wu1n);
    }
    k_sr<<<(N_ATOMS + 127) / 128, 256, 0, stream>>>(h, row_ptr, edge_slot, Wr, b_read, out);
}

// Round 12
// 660.621 us; speedup vs baseline: 1.0760x; 1.0760x over previous
//
#include <hip/hip_runtime.h>
#include <stdint.h>
#include <stddef.h>

#define N_ATOMS 50000
#define N_EDGES 524288
#define FA 133
#define FB 14
#define H 128
#define DEPTH 3
#define KI 160   /* 133 padded to multiple of 32 */
#define KB 32    /* 14 padded to 32 */
#define KR 128
#define SCAN_NB 98   /* ceil(50000/512) */

typedef __attribute__((ext_vector_type(8))) __bf16 bf16x8;
typedef __attribute__((ext_vector_type(4))) float f32x4;

__device__ __forceinline__ uint16_t f2bf(float f) {
    uint32_t u = __builtin_bit_cast(uint32_t, f);
    return (uint16_t)((u + 0x7FFFu + ((u >> 16) & 1u)) >> 16);
}
__device__ __forceinline__ float bf2f(uint16_t h) {
    return __builtin_bit_cast(float, (uint32_t)h << 16);
}
__device__ __forceinline__ uint32_t pack2(float a, float b) {
#if __has_builtin(__builtin_amdgcn_cvt_pk_bf16_f32)
    typedef __attribute__((ext_vector_type(2))) __bf16 bf16x2_t;
    bf16x2_t v = __builtin_amdgcn_cvt_pk_bf16_f32(a, b);
    return __builtin_bit_cast(uint32_t, v);
#else
    return (uint32_t)f2bf(a) | ((uint32_t)f2bf(b) << 16);
#endif
}

// async 16B global -> LDS (dest = wave-uniform base + lane*16)
__device__ __forceinline__ void async_load16(const uint16_t* g, uint16_t* l) {
    __builtin_amdgcn_global_load_lds(
        (const __attribute__((address_space(1))) uint32_t*)(const void*)g,
        (__attribute__((address_space(3))) uint32_t*)(void*)l,
        16, 0, 0);
}

// ---- weight conversion ----------------------------------------------------
__global__ void k_weights(const float* __restrict__ Wi_f,
                          const float* __restrict__ Wu_f,
                          const float* __restrict__ Wr_f,
                          uint16_t* __restrict__ Wa,
                          uint16_t* __restrict__ Wb,
                          uint16_t* __restrict__ Wu0,
                          uint16_t* __restrict__ Wu1,
                          uint16_t* __restrict__ Wu1n,
                          uint16_t* __restrict__ Wr) {
    const int O0 = H * KI, O1 = O0 + H * KB, O2 = O1 + H * 128,
              O3 = O2 + H * 128, O4 = O3 + H * 128, O5 = O4 + H * KR;
    int i = blockIdx.x * 256 + threadIdx.x;
    if (i < O0) {
        int o = i / KI, k = i - o * KI;
        Wa[i] = f2bf((k < FA) ? Wi_f[o * (FA + FB) + k] : 0.f);
    } else if (i < O1) {
        int j = i - O0;
        int o = j >> 5, k = j & 31;
        Wb[j] = f2bf((k < FB) ? Wi_f[o * (FA + FB) + FA + k] : 0.f);
    } else if (i < O2) {
        int j = i - O1;
        int o = j >> 7, k = j & 127;
        Wu0[j] = f2bf(Wu_f[o * 256 + k]);
    } else if (i < O3) {
        int j = i - O2;
        int o = j >> 7, k = j & 127;
        Wu1[j] = f2bf(Wu_f[o * 256 + 128 + k]);
    } else if (i < O4) {
        int j = i - O3;
        int o = j >> 7, k = j & 127;
        Wu1n[j] = f2bf(-Wu_f[o * 256 + 128 + k]);
    } else if (i < O5) {
        int j = i - O4;
        Wr[j] = f2bf(Wr_f[j]);
    }
}

// ---------------- CSR build ------------------------------------------------
__global__ void k_hist(const int* __restrict__ dstv, int* __restrict__ counts) {
    int e = blockIdx.x * 256 + threadIdx.x;
    if (e < N_EDGES) atomicAdd(&counts[dstv[e]], 1);
}

__global__ void k_scan1(const int* __restrict__ counts,
                        int* __restrict__ lscan, int* __restrict__ partials) {
    __shared__ int s[512];
    const int t = threadIdx.x, b = blockIdx.x;
    const int i = b * 512 + t;
    const int c = (i < N_ATOMS) ? counts[i] : 0;
    s[t] = c;
    __syncthreads();
    for (int off = 1; off < 512; off <<= 1) {
        int u = (t >= off) ? s[t - off] : 0;
        __syncthreads();
        s[t] += u;
        __syncthreads();
    }
    lscan[i] = s[t] - c;  // exclusive
    if (t == 511) partials[b] = s[511];
}

__global__ void k_scan2(const int* __restrict__ partials, int* __restrict__ poff) {
    __shared__ int s[128];
    const int t = threadIdx.x;
    const int v = (t < SCAN_NB) ? partials[t] : 0;
    s[t] = v;
    __syncthreads();
    for (int off = 1; off < 128; off <<= 1) {
        int u = (t >= off) ? s[t - off] : 0;
        __syncthreads();
        s[t] += u;
        __syncthreads();
    }
    poff[t] = s[t] - v;  // exclusive
}

__global__ void k_scan3(const int* __restrict__ lscan, const int* __restrict__ poff,
                        int* __restrict__ row_ptr, int* __restrict__ nxt) {
    const int i = blockIdx.x * 512 + threadIdx.x;
    if (i < N_ATOMS) {
        const int v = poff[blockIdx.x] + lscan[i];
        row_ptr[i] = v;
        nxt[i] = v;
    }
    if (i == 0) row_ptr[N_ATOMS] = N_EDGES;
}

__global__ void k_scatter(const int* __restrict__ dstv, int* __restrict__ nxt,
                          int* __restrict__ edge_slot) {
    int e = blockIdx.x * 256 + threadIdx.x;
    if (e < N_EDGES) {
        int pos = atomicAdd(&nxt[dstv[e]], 1);
        edge_slot[pos] = e;
    }
}

// ---- P = atom @ Wa^T (dense, gather-free) ---------------------------------
__global__ __launch_bounds__(256, 3) void k_atom_gemm(
    const float* __restrict__ atom, const uint16_t* __restrict__ Wa,
    uint16_t* __restrict__ P) {
    __shared__ __align__(16) uint16_t A[128 * 168];
    const int t = threadIdx.x;
    const int base = blockIdx.x * 128;
    if (t < 128) {
        for (int c = FA; c < KI; ++c) A[t * 168 + c] = 0;
    }
    for (int j = 0; j < 67; ++j) {
        int f = j * 256 + t;
        if (f < 128 * FA) {
            int row = f / FA, col = f - row * FA;
            int a = base + row;
            float v = (a < N_ATOMS) ? atom[(size_t)a * FA + col] : 0.f;
            A[row * 168 + col] = f2bf(v);
        }
    }
    __syncthreads();
    const int w = t >> 6, lane = t & 63;
    const int wm = w >> 1, wn = w & 1;
    const int l15 = lane & 15, q = lane >> 4;
    f32x4 acc[4][4];
    const f32x4 z = {0.f, 0.f, 0.f, 0.f};
    for (int i = 0; i < 4; ++i)
        for (int jj = 0; jj < 4; ++jj) acc[i][jj] = z;
#pragma unroll
    for (int ks = 0; ks < 5; ++ks) {
        const int kk = ks * 32 + q * 8;
        bf16x8 a[4], b[4];
#pragma unroll
        for (int i = 0; i < 4; ++i)
            a[i] = *(const bf16x8*)&A[(wm * 64 + i * 16 + l15) * 168 + kk];
#pragma unroll
        for (int jj = 0; jj < 4; ++jj)
            b[jj] = *(const bf16x8*)&Wa[(wn * 64 + jj * 16 + l15) * KI + kk];
#pragma unroll
        for (int i = 0; i < 4; ++i)
#pragma unroll
            for (int jj = 0; jj < 4; ++jj)
                acc[i][jj] = __builtin_amdgcn_mfma_f32_16x16x32_bf16(a[i], b[jj], acc[i][jj], 0, 0, 0);
    }
    __syncthreads();
#pragma unroll
    for (int jj = 0; jj < 4; ++jj) {
        const int col = wn * 64 + jj * 16 + l15;
#pragma unroll
        for (int i = 0; i < 4; ++i)
#pragma unroll
            for (int r = 0; r < 4; ++r) {
                const int row = wm * 64 + i * 16 + q * 4 + r;
                A[row * 136 + col] = f2bf(acc[i][jj][r]);
            }
    }
    __syncthreads();
    for (int j = 0; j < 8; ++j) {
        int c = j * 256 + t;
        int row = c >> 4, kc = c & 15;
        *(bf16x8*)(P + (size_t)(base + row) * H + kc * 8) =
            *(const bf16x8*)&A[row * 136 + kc * 8];
    }
}

// ---- h0 = relu(P[src] + bond @ Wb^T + b_init) — R9 version ----------------
__global__ __launch_bounds__(256, 3) void k_edge_init(
    const float* __restrict__ bond, const int* __restrict__ srcv,
    const uint16_t* __restrict__ Wb, const uint16_t* __restrict__ P,
    const float* __restrict__ b_init, uint16_t* __restrict__ h_out) {
    __shared__ __align__(16) uint16_t Pl[128 * 136];
    __shared__ __align__(16) uint16_t Bb[128 * 40];
    __shared__ int src_lds[128];
    const int t = threadIdx.x;
    const int base = blockIdx.x * 128;
    if (t < 128) {
        src_lds[t] = srcv[base + t];
        for (int c = FB; c < KB; ++c) Bb[t * 40 + c] = 0;
    }
    for (int j = 0; j < 7; ++j) {
        int f = j * 256 + t;
        int row = f / FB, col = f - row * FB;
        Bb[row * 40 + col] = f2bf(bond[(size_t)(base + row) * FB + col]);
    }
    __syncthreads();
    for (int j = 0; j < 8; ++j) {
        int task = j * 256 + t;
        int row = task >> 4, seg = task & 15;
        *(bf16x8*)&Pl[row * 136 + seg * 8] =
            *(const bf16x8*)(P + (size_t)src_lds[row] * H + seg * 8);
    }
    const int w = t >> 6, lane = t & 63;
    const int wm = w >> 1, wn = w & 1;
    const int l15 = lane & 15, q = lane >> 4;
    f32x4 acc[4][4];
    const f32x4 z = {0.f, 0.f, 0.f, 0.f};
    for (int i = 0; i < 4; ++i)
        for (int jj = 0; jj < 4; ++jj) acc[i][jj] = z;
    {
        const int kk = q * 8;
        bf16x8 a[4], b[4];
#pragma unroll
        for (int i = 0; i < 4; ++i)
            a[i] = *(const bf16x8*)&Bb[(wm * 64 + i * 16 + l15) * 40 + kk];
#pragma unroll
        for (int jj = 0; jj < 4; ++jj)
            b[jj] = *(const bf16x8*)&Wb[(wn * 64 + jj * 16 + l15) * KB + kk];
#pragma unroll
        for (int i = 0; i < 4; ++i)
#pragma unroll
            for (int jj = 0; jj < 4; ++jj)
                acc[i][jj] = __builtin_amdgcn_mfma_f32_16x16x32_bf16(a[i], b[jj], acc[i][jj], 0, 0, 0);
    }
    __syncthreads();  // Pl gather complete
#pragma unroll
    for (int jj = 0; jj < 4; ++jj) {
        const int col = wn * 64 + jj * 16 + l15;
        const float bias = b_init[col];
#pragma unroll
        for (int i = 0; i < 4; ++i)
#pragma unroll
            for (int r = 0; r < 4; ++r) {
                const int row = wm * 64 + i * 16 + q * 4 + r;
                float v = acc[i][jj][r] + bf2f(Pl[row * 136 + col]) + bias;
                Pl[row * 136 + col] = f2bf(v > 0.f ? v : 0.f);
            }
    }
    __syncthreads();
    for (int j = 0; j < 8; ++j) {
        int c = j * 256 + t;
        int row = c >> 4, kc = c & 15;
        *(bf16x8*)(h_out + (size_t)(base + row) * H + kc * 8) =
            *(const bf16x8*)&Pl[row * 136 + kc * 8];
    }
}

// ---- FUSED segsum + G GEMM: G[a] = (sum_{dst==a} h) @ Wu1^T + b_upd -------
// segsum = R9's 4-deep per-atom loop (R10 8-deep and R11 streamed both
// regressed); bias folded into G (k_update measured faster without bias).
__global__ __launch_bounds__(256, 4) void k_sg(
    const uint16_t* __restrict__ h, const int* __restrict__ row_ptr,
    const int* __restrict__ edge_slot, const uint16_t* __restrict__ Wu1,
    const float* __restrict__ b_upd, uint16_t* __restrict__ G) {
    __shared__ __align__(16) uint16_t S[128 * 136];
    const int t = threadIdx.x;
    const int base = blockIdx.x * 128;
    const int qw = t >> 4, ql = t & 15;
    for (int s = 0; s < 8; ++s) {
        const int local = qw * 8 + s;
        const int a = base + local;
        float acc[8];
#pragma unroll
        for (int i = 0; i < 8; ++i) acc[i] = 0.f;
        if (a < N_ATOMS) {
            const int s0 = row_ptr[a], s1 = row_ptr[a + 1];
            int e[4];
#pragma unroll
            for (int i = 0; i < 4; ++i)
                e[i] = (s0 + i < s1) ? edge_slot[s0 + i] : -1;
            int p = s0;
            while (p < s1) {
                bf16x8 v[4];
                bool has[4];
#pragma unroll
                for (int i = 0; i < 4; ++i) {
                    has[i] = (p + i < s1);
                    if (has[i]) v[i] = *(const bf16x8*)(h + (size_t)e[i] * H + ql * 8);
                }
#pragma unroll
                for (int i = 0; i < 4; ++i) {
                    int np = p + 4 + i;
                    e[i] = (np < s1) ? edge_slot[np] : -1;
                }
#pragma unroll
                for (int i = 0; i < 4; ++i)
                    if (has[i]) {
#pragma unroll
                        for (int k = 0; k < 8; ++k) acc[k] += (float)v[i][k];
                    }
                p += 4;
            }
        }
        uint4 o;
        o.x = pack2(acc[0], acc[1]);
        o.y = pack2(acc[2], acc[3]);
        o.z = pack2(acc[4], acc[5]);
        o.w = pack2(acc[6], acc[7]);
        *(uint4*)&S[local * 136 + ql * 8] = o;
    }
    __syncthreads();
    const int w = t >> 6, lane = t & 63;
    const int wm = w >> 1, wn = w & 1;
    const int l15 = lane & 15, q = lane >> 4;
    f32x4 acc[4][4];
    const f32x4 z = {0.f, 0.f, 0.f, 0.f};
    for (int i = 0; i < 4; ++i)
        for (int jj = 0; jj < 4; ++jj) acc[i][jj] = z;
#pragma unroll
    for (int ks = 0; ks < 4; ++ks) {
        const int kk = ks * 32 + q * 8;
        bf16x8 a[4], b[4];
#pragma unroll
        for (int i = 0; i < 4; ++i)
            a[i] = *(const bf16x8*)&S[(wm * 64 + i * 16 + l15) * 136 + kk];
#pragma unroll
        for (int jj = 0; jj < 4; ++jj)
            b[jj] = *(const bf16x8*)&Wu1[(wn * 64 + jj * 16 + l15) * 128 + kk];
#pragma unroll
        for (int i = 0; i < 4; ++i)
#pragma unroll
            for (int jj = 0; jj < 4; ++jj)
                acc[i][jj] = __builtin_amdgcn_mfma_f32_16x16x32_bf16(a[i], b[jj], acc[i][jj], 0, 0, 0);
    }
    __syncthreads();
#pragma unroll
    for (int jj = 0; jj < 4; ++jj) {
        const int col = wn * 64 + jj * 16 + l15;
        const float bias = b_upd[col];
#pragma unroll
        for (int i = 0; i < 4; ++i)
#pragma unroll
            for (int r = 0; r < 4; ++r) {
                const int row = wm * 64 + i * 16 + q * 4 + r;
                S[row * 136 + col] = f2bf(acc[i][jj][r] + bias);
            }
    }
    __syncthreads();
    for (int j = 0; j < 8; ++j) {
        int c = j * 256 + t;
        int row = c >> 4, kc = c & 15;
        int a_idx = base + row;
        if (a_idx < N_ATOMS)
            *(bf16x8*)(G + (size_t)a_idx * H + kc * 8) =
                *(const bf16x8*)&S[row * 136 + kc * 8];
    }
}

// ---- update: h' = relu(h@Wu0^T + h[e^1]@(-Wu1)^T + G[src]) ----------------
// (G carries the bias). R11 version — 99.0 us, zero LDS bank conflicts.
__global__ __launch_bounds__(512, 2) void k_update(
    uint16_t* __restrict__ h_io, const uint16_t* __restrict__ G,
    const int* __restrict__ srcv, const uint16_t* __restrict__ Wu0,
    const uint16_t* __restrict__ Wu1n) {
    __shared__ __align__(16) uint16_t A[128 * 128];   // swizzled h tile / acc park
    __shared__ __align__(16) uint16_t Gl[128 * 128];  // gathered G rows
    const int t = threadIdx.x;
    const int base = blockIdx.x * 128;
    const int w = t >> 6, lane = t & 63;
#pragma unroll
    for (int j = 0; j < 4; ++j) {
        const int task = j * 512 + t;
        const int row = task >> 4, sp = task & 15;
        const int sl = sp ^ (row & 15);
        const int wavebase = j * 512 + w * 64;  // uniform per wave
        async_load16(h_io + (size_t)(base + row) * H + sl * 8, A + wavebase * 8);
        const int s = srcv[base + row];
        async_load16(G + (size_t)s * H + sp * 8, Gl + wavebase * 8);
    }
    __syncthreads();  // single drain: h + G land together
    const int wm = w >> 2, wn = w & 3;
    const int l15 = lane & 15, q = lane >> 4;
    const int l15r = l15 ^ 1;
    f32x4 acc[4][2];
    const f32x4 z = {0.f, 0.f, 0.f, 0.f};
    for (int i = 0; i < 4; ++i)
        for (int jj = 0; jj < 2; ++jj) acc[i][jj] = z;
#pragma unroll
    for (int ks = 0; ks < 4; ++ks) {
        const int ck = ks * 4 + q;
        const int kk = ck * 8;
        bf16x8 a[4], b[2];
#pragma unroll
        for (int i = 0; i < 4; ++i)
            a[i] = *(const bf16x8*)&A[(wm * 64 + i * 16 + l15) * 128 + (ck ^ l15) * 8];
#pragma unroll
        for (int jj = 0; jj < 2; ++jj)
            b[jj] = *(const bf16x8*)&Wu0[(wn * 32 + jj * 16 + l15) * 128 + kk];
#pragma unroll
        for (int i = 0; i < 4; ++i)
#pragma unroll
            for (int jj = 0; jj < 2; ++jj)
                acc[i][jj] = __builtin_amdgcn_mfma_f32_16x16x32_bf16(a[i], b[jj], acc[i][jj], 0, 0, 0);
    }
#pragma unroll
    for (int ks = 0; ks < 4; ++ks) {
        const int ck = ks * 4 + q;
        const int kk = ck * 8;
        bf16x8 a[4], b[2];
#pragma unroll
        for (int i = 0; i < 4; ++i)
            a[i] = *(const bf16x8*)&A[(wm * 64 + i * 16 + l15r) * 128 + (ck ^ l15r) * 8];
#pragma unroll
        for (int jj = 0; jj < 2; ++jj)
            b[jj] = *(const bf16x8*)&Wu1n[(wn * 32 + jj * 16 + l15) * 128 + kk];
#pragma unroll
        for (int i = 0; i < 4; ++i)
#pragma unroll
            for (int jj = 0; jj < 2; ++jj)
                acc[i][jj] = __builtin_amdgcn_mfma_f32_16x16x32_bf16(a[i], b[jj], acc[i][jj], 0, 0, 0);
    }
    __syncthreads();  // all A reads done
#pragma unroll
    for (int jj = 0; jj < 2; ++jj) {
        const int col = wn * 32 + jj * 16 + l15;
        const int cc = col >> 3, c7 = col & 7;
#pragma unroll
        for (int i = 0; i < 4; ++i)
#pragma unroll
            for (int r = 0; r < 4; ++r) {
                const int row = wm * 64 + i * 16 + q * 4 + r;
                A[row * 128 + (cc ^ (row & 15)) * 8 + c7] = f2bf(acc[i][jj][r]);
            }
    }
    __syncthreads();
#pragma unroll
    for (int j = 0; j < 4; ++j) {
        const int task = j * 512 + t;
        const int row = task >> 4, sl = task & 15;
        const bf16x8 a8 = *(const bf16x8*)&A[row * 128 + (sl ^ (row & 15)) * 8];
        const bf16x8 g8 = *(const bf16x8*)&Gl[row * 128 + sl * 8];
        uint4 pck;
        uint32_t parts[4];
#pragma unroll
        for (int hw = 0; hw < 4; ++hw) {
            float v0 = (float)a8[hw * 2] + (float)g8[hw * 2];
            float v1 = (float)a8[hw * 2 + 1] + (float)g8[hw * 2 + 1];
            v0 = v0 > 0.f ? v0 : 0.f;
            v1 = v1 > 0.f ? v1 : 0.f;
            parts[hw] = pack2(v0, v1);
        }
        pck.x = parts[0]; pck.y = parts[1]; pck.z = parts[2]; pck.w = parts[3];
        *(uint4*)(h_io + (size_t)(base + row) * H + sl * 8) = pck;
    }
}

// ---- FUSED final segsum + readout (R9 segsum) -----------------------------
__global__ __launch_bounds__(256, 4) void k_sr(
    const uint16_t* __restrict__ h, const int* __restrict__ row_ptr,
    const int* __restrict__ edge_slot, const uint16_t* __restrict__ Wr,
    const float* __restrict__ b_read, float* __restrict__ out) {
    __shared__ __align__(16) uint16_t S[128 * 136];
    __shared__ float col_lds[128];
    const int t = threadIdx.x;
    const int base = blockIdx.x * 128;
    const int qw = t >> 4, ql = t & 15;
    if (t < 128) col_lds[t] = 0.f;
    for (int s = 0; s < 8; ++s) {
        const int local = qw * 8 + s;
        const int a = base + local;
        float acc[8];
#pragma unroll
        for (int i = 0; i < 8; ++i) acc[i] = 0.f;
        if (a < N_ATOMS) {
            const int s0 = row_ptr[a], s1 = row_ptr[a + 1];
            int e[4];
#pragma unroll
            for (int i = 0; i < 4; ++i)
                e[i] = (s0 + i < s1) ? edge_slot[s0 + i] : -1;
            int p = s0;
            while (p < s1) {
                bf16x8 v[4];
                bool has[4];
#pragma unroll
                for (int i = 0; i < 4; ++i) {
                    has[i] = (p + i < s1);
                    if (has[i]) v[i] = *(const bf16x8*)(h + (size_t)e[i] * H + ql * 8);
                }
#pragma unroll
                for (int i = 0; i < 4; ++i) {
                    int np = p + 4 + i;
                    e[i] = (np < s1) ? edge_slot[np] : -1;
                }
#pragma unroll
                for (int i = 0; i < 4; ++i)
                    if (has[i]) {
#pragma unroll
                        for (int k = 0; k < 8; ++k) acc[k] += (float)v[i][k];
                    }
                p += 4;
            }
        }
        uint4 o;
        o.x = pack2(acc[0], acc[1]);
        o.y = pack2(acc[2], acc[3]);
        o.z = pack2(acc[4], acc[5]);
        o.w = pack2(acc[6], acc[7]);
        *(uint4*)&S[local * 136 + ql * 8] = o;
    }
    __syncthreads();
    const int w = t >> 6, lane = t & 63;
    const int wm = w >> 1, wn = w & 1;
    const int l15 = lane & 15, q = lane >> 4;
    f32x4 acc[4][4];
    const f32x4 z = {0.f, 0.f, 0.f, 0.f};
    for (int i = 0; i < 4; ++i)
        for (int jj = 0; jj < 4; ++jj) acc[i][jj] = z;
#pragma unroll
    for (int ks = 0; ks < 4; ++ks) {
        const int kk = ks * 32 + q * 8;
        bf16x8 a[4], b[4];
#pragma unroll
        for (int i = 0; i < 4; ++i)
            a[i] = *(const bf16x8*)&S[(wm * 64 + i * 16 + l15) * 136 + kk];
#pragma unroll
        for (int jj = 0; jj < 4; ++jj)
            b[jj] = *(const bf16x8*)&Wr[(wn * 64 + jj * 16 + l15) * KR + kk];
#pragma unroll
        for (int i = 0; i < 4; ++i)
#pragma unroll
            for (int jj = 0; jj < 4; ++jj)
                acc[i][jj] = __builtin_amdgcn_mfma_f32_16x16x32_bf16(a[i], b[jj], acc[i][jj], 0, 0, 0);
    }
#pragma unroll
    for (int jj = 0; jj < 4; ++jj) {
        const int col = wn * 64 + jj * 16 + l15;
        const float bias = b_read[col];
        float s = 0.f;
#pragma unroll
        for (int i = 0; i < 4; ++i)
#pragma unroll
            for (int r = 0; r < 4; ++r) {
                const int a_idx = base + wm * 64 + i * 16 + q * 4 + r;
                if (a_idx < N_ATOMS) {
                    float v = acc[i][jj][r] + bias;
                    s += (v > 0.f) ? v : 0.f;
                }
            }
        atomicAdd(&col_lds[col], s);
    }
    __syncthreads();
    if (t < 128) atomicAdd(&out[t], col_lds[t]);
}

// ---------------- launch ---------------------------------------------------
extern "C" void kernel_launch(void* const* d_in, const int* in_sizes, int n_in,
                              void* d_out, int out_size, void* d_ws, size_t ws_size,
                              hipStream_t stream) {
    (void)in_sizes; (void)n_in; (void)out_size; (void)ws_size;
    const float* atom   = (const float*)d_in[0];
    const float* bond   = (const float*)d_in[1];
    const int* edge_idx = (const int*)d_in[2];
    const float* W_init = (const float*)d_in[3];
    const float* b_init = (const float*)d_in[4];
    const float* W_upd  = (const float*)d_in[5];
    const float* b_upd  = (const float*)d_in[6];
    const float* W_read = (const float*)d_in[7];
    const float* b_read = (const float*)d_in[8];
    float* out = (float*)d_out;

    char* ws = (char*)d_ws;
    constexpr size_t SZ_H    = (size_t)N_EDGES * H * 2;            // 134217728
    constexpr size_t OFF_H   = 0;
    constexpr size_t OFF_P   = OFF_H + SZ_H;
    constexpr size_t OFF_G   = OFF_P + (size_t)N_ATOMS * H * 2;
    constexpr size_t OFF_WA  = OFF_G + (size_t)N_ATOMS * H * 2;
    constexpr size_t OFF_WB  = OFF_WA + (size_t)H * KI * 2;
    constexpr size_t OFF_WU0 = OFF_WB + (size_t)H * KB * 2;
    constexpr size_t OFF_WU1 = OFF_WU0 + (size_t)H * 128 * 2;
    constexpr size_t OFF_WU1N= OFF_WU1 + (size_t)H * 128 * 2;
    constexpr size_t OFF_WR  = OFF_WU1N + (size_t)H * 128 * 2;
    constexpr size_t OFF_CNT = OFF_WR + (size_t)H * KR * 2;
    constexpr size_t OFF_RP  = OFF_CNT + 200192;
    constexpr size_t OFF_NXT = OFF_RP + 200704;
    constexpr size_t OFF_ES  = OFF_NXT + 200192;
    constexpr size_t OFF_LS  = OFF_ES + (size_t)N_EDGES * 4;
    constexpr size_t OFF_PT  = OFF_LS + 512 * SCAN_NB * 4;
    constexpr size_t OFF_PO  = OFF_PT + 512;

    uint16_t* h     = (uint16_t*)(ws + OFF_H);
    uint16_t* P     = (uint16_t*)(ws + OFF_P);
    uint16_t* G     = (uint16_t*)(ws + OFF_G);
    uint16_t* Wa    = (uint16_t*)(ws + OFF_WA);
    uint16_t* Wb    = (uint16_t*)(ws + OFF_WB);
    uint16_t* Wu0   = (uint16_t*)(ws + OFF_WU0);
    uint16_t* Wu1   = (uint16_t*)(ws + OFF_WU1);
    uint16_t* Wu1n  = (uint16_t*)(ws + OFF_WU1N);
    uint16_t* Wr    = (uint16_t*)(ws + OFF_WR);
    int* counts     = (int*)(ws + OFF_CNT);
    int* row_ptr    = (int*)(ws + OFF_RP);
    int* nxt        = (int*)(ws + OFF_NXT);
    int* edge_slot  = (int*)(ws + OFF_ES);
    int* lscan      = (int*)(ws + OFF_LS);
    int* partials   = (int*)(ws + OFF_PT);
    int* poff       = (int*)(ws + OFF_PO);

    const int* srcv = edge_idx;
    const int* dstv = edge_idx + N_EDGES;

    hipMemsetAsync(counts, 0, N_ATOMS * sizeof(int), stream);
    hipMemsetAsync(d_out, 0, H * sizeof(float), stream);

    const int NW = H * KI + H * KB + 3 * H * 128 + H * KR;  // 90112
    k_weights<<<(NW + 255) / 256, 256, 0, stream>>>(
        W_init, W_upd, W_read, Wa, Wb, Wu0, Wu1, Wu1n, Wr);
    k_hist<<<(N_EDGES + 255) / 256, 256, 0, stream>>>(dstv, counts);
    k_scan1<<<SCAN_NB, 512, 0, stream>>>(counts, lscan, partials);
    k_scan2<<<1, 128, 0, stream>>>(partials, poff);
    k_scan3<<<SCAN_NB, 512, 0, stream>>>(lscan, poff, row_ptr, nxt);
    k_scatter<<<(N_EDGES + 255) / 256, 256, 0, stream>>>(dstv, nxt, edge_slot);

    k_atom_gemm<<<(N_ATOMS + 127) / 128, 256, 0, stream>>>(atom, Wa, P);
    k_edge_init<<<N_EDGES / 128, 256, 0, stream>>>(bond, srcv, Wb, P, b_init, h);

    for (int d = 0; d < DEPTH; ++d) {
        k_sg<<<(N_ATOMS + 127) / 128, 256, 0, stream>>>(h, row_ptr, edge_slot, Wu1, b_upd, G);
        k_update<<<N_EDGES / 128, 512, 0, stream>>>(h, G, srcv, Wu0, Wu1n);
    }
    k_sr<<<(N_ATOMS + 127) / 128, 256, 0, stream>>>(h, row_ptr, edge_slot, Wr, b_read, out);
}

// Round 13
// 648.375 us; speedup vs baseline: 1.0963x; 1.0189x over previous
//
#include <hip/hip_runtime.h>
#include <stdint.h>
#include <stddef.h>

#define N_ATOMS 50000
#define N_EDGES 524288
#define FA 133
#define FB 14
#define H 128
#define DEPTH 3
#define KI 160   /* 133 padded to multiple of 32 */
#define KB 32    /* 14 padded to 32 */
#define KR 128
#define SCAN_NB 98   /* ceil(50000/512) */

typedef __attribute__((ext_vector_type(8))) __bf16 bf16x8;
typedef __attribute__((ext_vector_type(4))) float f32x4;

__device__ __forceinline__ uint16_t f2bf(float f) {
    uint32_t u = __builtin_bit_cast(uint32_t, f);
    return (uint16_t)((u + 0x7FFFu + ((u >> 16) & 1u)) >> 16);
}
__device__ __forceinline__ float bf2f(uint16_t h) {
    return __builtin_bit_cast(float, (uint32_t)h << 16);
}
__device__ __forceinline__ uint32_t pack2(float a, float b) {
#if __has_builtin(__builtin_amdgcn_cvt_pk_bf16_f32)
    typedef __attribute__((ext_vector_type(2))) __bf16 bf16x2_t;
    bf16x2_t v = __builtin_amdgcn_cvt_pk_bf16_f32(a, b);
    return __builtin_bit_cast(uint32_t, v);
#else
    return (uint32_t)f2bf(a) | ((uint32_t)f2bf(b) << 16);
#endif
}

// async 16B global -> LDS (dest = wave-uniform base + lane*16)
__device__ __forceinline__ void async_load16(const uint16_t* g, uint16_t* l) {
    __builtin_amdgcn_global_load_lds(
        (const __attribute__((address_space(1))) uint32_t*)(const void*)g,
        (__attribute__((address_space(3))) uint32_t*)(void*)l,
        16, 0, 0);
}

// ---- weight conversion ----------------------------------------------------
__global__ void k_weights(const float* __restrict__ Wi_f,
                          const float* __restrict__ Wu_f,
                          const float* __restrict__ Wr_f,
                          uint16_t* __restrict__ Wa,
                          uint16_t* __restrict__ Wb,
                          uint16_t* __restrict__ Wu0,
                          uint16_t* __restrict__ Wu1,
                          uint16_t* __restrict__ Wu1n,
                          uint16_t* __restrict__ Wr) {
    const int O0 = H * KI, O1 = O0 + H * KB, O2 = O1 + H * 128,
              O3 = O2 + H * 128, O4 = O3 + H * 128, O5 = O4 + H * KR;
    int i = blockIdx.x * 256 + threadIdx.x;
    if (i < O0) {
        int o = i / KI, k = i - o * KI;
        Wa[i] = f2bf((k < FA) ? Wi_f[o * (FA + FB) + k] : 0.f);
    } else if (i < O1) {
        int j = i - O0;
        int o = j >> 5, k = j & 31;
        Wb[j] = f2bf((k < FB) ? Wi_f[o * (FA + FB) + FA + k] : 0.f);
    } else if (i < O2) {
        int j = i - O1;
        int o = j >> 7, k = j & 127;
        Wu0[j] = f2bf(Wu_f[o * 256 + k]);
    } else if (i < O3) {
        int j = i - O2;
        int o = j >> 7, k = j & 127;
        Wu1[j] = f2bf(Wu_f[o * 256 + 128 + k]);
    } else if (i < O4) {
        int j = i - O3;
        int o = j >> 7, k = j & 127;
        Wu1n[j] = f2bf(-Wu_f[o * 256 + 128 + k]);
    } else if (i < O5) {
        int j = i - O4;
        Wr[j] = f2bf(Wr_f[j]);
    }
}

// ---------------- CSR build ------------------------------------------------
__global__ void k_hist(const int* __restrict__ dstv, int* __restrict__ counts) {
    int e = blockIdx.x * 256 + threadIdx.x;
    if (e < N_EDGES) atomicAdd(&counts[dstv[e]], 1);
}

__global__ void k_scan1(const int* __restrict__ counts,
                        int* __restrict__ lscan, int* __restrict__ partials) {
    __shared__ int s[512];
    const int t = threadIdx.x, b = blockIdx.x;
    const int i = b * 512 + t;
    const int c = (i < N_ATOMS) ? counts[i] : 0;
    s[t] = c;
    __syncthreads();
    for (int off = 1; off < 512; off <<= 1) {
        int u = (t >= off) ? s[t - off] : 0;
        __syncthreads();
        s[t] += u;
        __syncthreads();
    }
    lscan[i] = s[t] - c;  // exclusive
    if (t == 511) partials[b] = s[511];
}

__global__ void k_scan2(const int* __restrict__ partials, int* __restrict__ poff) {
    __shared__ int s[128];
    const int t = threadIdx.x;
    const int v = (t < SCAN_NB) ? partials[t] : 0;
    s[t] = v;
    __syncthreads();
    for (int off = 1; off < 128; off <<= 1) {
        int u = (t >= off) ? s[t - off] : 0;
        __syncthreads();
        s[t] += u;
        __syncthreads();
    }
    poff[t] = s[t] - v;  // exclusive
}

__global__ void k_scan3(const int* __restrict__ lscan, const int* __restrict__ poff,
                        int* __restrict__ row_ptr, int* __restrict__ nxt) {
    const int i = blockIdx.x * 512 + threadIdx.x;
    if (i < N_ATOMS) {
        const int v = poff[blockIdx.x] + lscan[i];
        row_ptr[i] = v;
        nxt[i] = v;
    }
    if (i == 0) row_ptr[N_ATOMS] = N_EDGES;
}

__global__ void k_scatter(const int* __restrict__ dstv, int* __restrict__ nxt,
                          int* __restrict__ edge_slot) {
    int e = blockIdx.x * 256 + threadIdx.x;
    if (e < N_EDGES) {
        int pos = atomicAdd(&nxt[dstv[e]], 1);
        edge_slot[pos] = e;
    }
}

// ---- P = atom @ Wa^T (dense, gather-free) ---------------------------------
__global__ __launch_bounds__(256, 3) void k_atom_gemm(
    const float* __restrict__ atom, const uint16_t* __restrict__ Wa,
    uint16_t* __restrict__ P) {
    __shared__ __align__(16) uint16_t A[128 * 168];
    const int t = threadIdx.x;
    const int base = blockIdx.x * 128;
    if (t < 128) {
        for (int c = FA; c < KI; ++c) A[t * 168 + c] = 0;
    }
    for (int j = 0; j < 67; ++j) {
        int f = j * 256 + t;
        if (f < 128 * FA) {
            int row = f / FA, col = f - row * FA;
            int a = base + row;
            float v = (a < N_ATOMS) ? atom[(size_t)a * FA + col] : 0.f;
            A[row * 168 + col] = f2bf(v);
        }
    }
    __syncthreads();
    const int w = t >> 6, lane = t & 63;
    const int wm = w >> 1, wn = w & 1;
    const int l15 = lane & 15, q = lane >> 4;
    f32x4 acc[4][4];
    const f32x4 z = {0.f, 0.f, 0.f, 0.f};
    for (int i = 0; i < 4; ++i)
        for (int jj = 0; jj < 4; ++jj) acc[i][jj] = z;
#pragma unroll
    for (int ks = 0; ks < 5; ++ks) {
        const int kk = ks * 32 + q * 8;
        bf16x8 a[4], b[4];
#pragma unroll
        for (int i = 0; i < 4; ++i)
            a[i] = *(const bf16x8*)&A[(wm * 64 + i * 16 + l15) * 168 + kk];
#pragma unroll
        for (int jj = 0; jj < 4; ++jj)
            b[jj] = *(const bf16x8*)&Wa[(wn * 64 + jj * 16 + l15) * KI + kk];
#pragma unroll
        for (int i = 0; i < 4; ++i)
#pragma unroll
            for (int jj = 0; jj < 4; ++jj)
                acc[i][jj] = __builtin_amdgcn_mfma_f32_16x16x32_bf16(a[i], b[jj], acc[i][jj], 0, 0, 0);
    }
    __syncthreads();
#pragma unroll
    for (int jj = 0; jj < 4; ++jj) {
        const int col = wn * 64 + jj * 16 + l15;
#pragma unroll
        for (int i = 0; i < 4; ++i)
#pragma unroll
            for (int r = 0; r < 4; ++r) {
                const int row = wm * 64 + i * 16 + q * 4 + r;
                A[row * 136 + col] = f2bf(acc[i][jj][r]);
            }
    }
    __syncthreads();
    for (int j = 0; j < 8; ++j) {
        int c = j * 256 + t;
        int row = c >> 4, kc = c & 15;
        *(bf16x8*)(P + (size_t)(base + row) * H + kc * 8) =
            *(const bf16x8*)&A[row * 136 + kc * 8];
    }
}

// ---- h0 = relu(P[src] + bond @ Wb^T + b_init) — R9 version ----------------
__global__ __launch_bounds__(256, 3) void k_edge_init(
    const float* __restrict__ bond, const int* __restrict__ srcv,
    const uint16_t* __restrict__ Wb, const uint16_t* __restrict__ P,
    const float* __restrict__ b_init, uint16_t* __restrict__ h_out) {
    __shared__ __align__(16) uint16_t Pl[128 * 136];
    __shared__ __align__(16) uint16_t Bb[128 * 40];
    __shared__ int src_lds[128];
    const int t = threadIdx.x;
    const int base = blockIdx.x * 128;
    if (t < 128) {
        src_lds[t] = srcv[base + t];
        for (int c = FB; c < KB; ++c) Bb[t * 40 + c] = 0;
    }
    for (int j = 0; j < 7; ++j) {
        int f = j * 256 + t;
        int row = f / FB, col = f - row * FB;
        Bb[row * 40 + col] = f2bf(bond[(size_t)(base + row) * FB + col]);
    }
    __syncthreads();
    for (int j = 0; j < 8; ++j) {
        int task = j * 256 + t;
        int row = task >> 4, seg = task & 15;
        *(bf16x8*)&Pl[row * 136 + seg * 8] =
            *(const bf16x8*)(P + (size_t)src_lds[row] * H + seg * 8);
    }
    const int w = t >> 6, lane = t & 63;
    const int wm = w >> 1, wn = w & 1;
    const int l15 = lane & 15, q = lane >> 4;
    f32x4 acc[4][4];
    const f32x4 z = {0.f, 0.f, 0.f, 0.f};
    for (int i = 0; i < 4; ++i)
        for (int jj = 0; jj < 4; ++jj) acc[i][jj] = z;
    {
        const int kk = q * 8;
        bf16x8 a[4], b[4];
#pragma unroll
        for (int i = 0; i < 4; ++i)
            a[i] = *(const bf16x8*)&Bb[(wm * 64 + i * 16 + l15) * 40 + kk];
#pragma unroll
        for (int jj = 0; jj < 4; ++jj)
            b[jj] = *(const bf16x8*)&Wb[(wn * 64 + jj * 16 + l15) * KB + kk];
#pragma unroll
        for (int i = 0; i < 4; ++i)
#pragma unroll
            for (int jj = 0; jj < 4; ++jj)
                acc[i][jj] = __builtin_amdgcn_mfma_f32_16x16x32_bf16(a[i], b[jj], acc[i][jj], 0, 0, 0);
    }
    __syncthreads();  // Pl gather complete
#pragma unroll
    for (int jj = 0; jj < 4; ++jj) {
        const int col = wn * 64 + jj * 16 + l15;
        const float bias = b_init[col];
#pragma unroll
        for (int i = 0; i < 4; ++i)
#pragma unroll
            for (int r = 0; r < 4; ++r) {
                const int row = wm * 64 + i * 16 + q * 4 + r;
                float v = acc[i][jj][r] + bf2f(Pl[row * 136 + col]) + bias;
                Pl[row * 136 + col] = f2bf(v > 0.f ? v : 0.f);
            }
    }
    __syncthreads();
    for (int j = 0; j < 8; ++j) {
        int c = j * 256 + t;
        int row = c >> 4, kc = c & 15;
        *(bf16x8*)(h_out + (size_t)(base + row) * H + kc * 8) =
            *(const bf16x8*)&Pl[row * 136 + kc * 8];
    }
}

// ---- FUSED segsum + G GEMM: G[a] = (sum_{dst==a} h) @ Wu1^T + b_upd -------
__global__ __launch_bounds__(256, 4) void k_sg(
    const uint16_t* __restrict__ h, const int* __restrict__ row_ptr,
    const int* __restrict__ edge_slot, const uint16_t* __restrict__ Wu1,
    const float* __restrict__ b_upd, uint16_t* __restrict__ G) {
    __shared__ __align__(16) uint16_t S[128 * 136];
    const int t = threadIdx.x;
    const int base = blockIdx.x * 128;
    const int qw = t >> 4, ql = t & 15;
    for (int s = 0; s < 8; ++s) {
        const int local = qw * 8 + s;
        const int a = base + local;
        float acc[8];
#pragma unroll
        for (int i = 0; i < 8; ++i) acc[i] = 0.f;
        if (a < N_ATOMS) {
            const int s0 = row_ptr[a], s1 = row_ptr[a + 1];
            int e[4];
#pragma unroll
            for (int i = 0; i < 4; ++i)
                e[i] = (s0 + i < s1) ? edge_slot[s0 + i] : -1;
            int p = s0;
            while (p < s1) {
                bf16x8 v[4];
                bool has[4];
#pragma unroll
                for (int i = 0; i < 4; ++i) {
                    has[i] = (p + i < s1);
                    if (has[i]) v[i] = *(const bf16x8*)(h + (size_t)e[i] * H + ql * 8);
                }
#pragma unroll
                for (int i = 0; i < 4; ++i) {
                    int np = p + 4 + i;
                    e[i] = (np < s1) ? edge_slot[np] : -1;
                }
#pragma unroll
                for (int i = 0; i < 4; ++i)
                    if (has[i]) {
#pragma unroll
                        for (int k = 0; k < 8; ++k) acc[k] += (float)v[i][k];
                    }
                p += 4;
            }
        }
        uint4 o;
        o.x = pack2(acc[0], acc[1]);
        o.y = pack2(acc[2], acc[3]);
        o.z = pack2(acc[4], acc[5]);
        o.w = pack2(acc[6], acc[7]);
        *(uint4*)&S[local * 136 + ql * 8] = o;
    }
    __syncthreads();
    const int w = t >> 6, lane = t & 63;
    const int wm = w >> 1, wn = w & 1;
    const int l15 = lane & 15, q = lane >> 4;
    f32x4 acc[4][4];
    const f32x4 z = {0.f, 0.f, 0.f, 0.f};
    for (int i = 0; i < 4; ++i)
        for (int jj = 0; jj < 4; ++jj) acc[i][jj] = z;
#pragma unroll
    for (int ks = 0; ks < 4; ++ks) {
        const int kk = ks * 32 + q * 8;
        bf16x8 a[4], b[4];
#pragma unroll
        for (int i = 0; i < 4; ++i)
            a[i] = *(const bf16x8*)&S[(wm * 64 + i * 16 + l15) * 136 + kk];
#pragma unroll
        for (int jj = 0; jj < 4; ++jj)
            b[jj] = *(const bf16x8*)&Wu1[(wn * 64 + jj * 16 + l15) * 128 + kk];
#pragma unroll
        for (int i = 0; i < 4; ++i)
#pragma unroll
            for (int jj = 0; jj < 4; ++jj)
                acc[i][jj] = __builtin_amdgcn_mfma_f32_16x16x32_bf16(a[i], b[jj], acc[i][jj], 0, 0, 0);
    }
    __syncthreads();
#pragma unroll
    for (int jj = 0; jj < 4; ++jj) {
        const int col = wn * 64 + jj * 16 + l15;
        const float bias = b_upd[col];
#pragma unroll
        for (int i = 0; i < 4; ++i)
#pragma unroll
            for (int r = 0; r < 4; ++r) {
                const int row = wm * 64 + i * 16 + q * 4 + r;
                S[row * 136 + col] = f2bf(acc[i][jj][r] + bias);
            }
    }
    __syncthreads();
    for (int j = 0; j < 8; ++j) {
        int c = j * 256 + t;
        int row = c >> 4, kc = c & 15;
        int a_idx = base + row;
        if (a_idx < N_ATOMS)
            *(bf16x8*)(G + (size_t)a_idx * H + kc * 8) =
                *(const bf16x8*)&S[row * 136 + kc * 8];
    }
}

// ---- update: h' = relu(h@Wu0^T + h[e^1]@(-Wu1)^T + G[src]) ----------------
// R13: G gathered into REGISTERS (g[4], issued after barrier-1, drained at
// the pre-park barrier behind both MFMA passes). Gl LDS buffer deleted
// (-32 KB). R6's version of this spilled because (256,4) capped regs at 128
// against acc[4][4]=64 AGPRs; here acc[4][2]=32 at (512,2) leaves room.
__global__ __launch_bounds__(512, 2) void k_update(
    uint16_t* __restrict__ h_io, const uint16_t* __restrict__ G,
    const int* __restrict__ srcv, const uint16_t* __restrict__ Wu0,
    const uint16_t* __restrict__ Wu1n) {
    __shared__ __align__(16) uint16_t A[128 * 128];   // swizzled h tile / acc park
    const int t = threadIdx.x;
    const int base = blockIdx.x * 128;
    const int w = t >> 6, lane = t & 63;
    // async stage h tile (swizzled); cache srcv for the G gather
    int s4[4];
#pragma unroll
    for (int j = 0; j < 4; ++j) {
        const int task = j * 512 + t;
        const int row = task >> 4, sp = task & 15;
        const int sl = sp ^ (row & 15);
        const int wavebase = j * 512 + w * 64;  // uniform per wave
        async_load16(h_io + (size_t)(base + row) * H + sl * 8, A + wavebase * 8);
        s4[j] = srcv[base + row];
    }
    __syncthreads();  // h drained
    // G gather -> registers; drains at the pre-park barrier (covered by MFMAs)
    bf16x8 g[4];
#pragma unroll
    for (int j = 0; j < 4; ++j) {
        const int sp = (j * 512 + t) & 15;
        g[j] = *(const bf16x8*)(G + (size_t)s4[j] * H + sp * 8);
    }
    const int wm = w >> 2, wn = w & 3;
    const int l15 = lane & 15, q = lane >> 4;
    const int l15r = l15 ^ 1;
    f32x4 acc[4][2];
    const f32x4 z = {0.f, 0.f, 0.f, 0.f};
    for (int i = 0; i < 4; ++i)
        for (int jj = 0; jj < 2; ++jj) acc[i][jj] = z;
#pragma unroll
    for (int ks = 0; ks < 4; ++ks) {
        const int ck = ks * 4 + q;
        const int kk = ck * 8;
        bf16x8 a[4], b[2];
#pragma unroll
        for (int i = 0; i < 4; ++i)
            a[i] = *(const bf16x8*)&A[(wm * 64 + i * 16 + l15) * 128 + (ck ^ l15) * 8];
#pragma unroll
        for (int jj = 0; jj < 2; ++jj)
            b[jj] = *(const bf16x8*)&Wu0[(wn * 32 + jj * 16 + l15) * 128 + kk];
#pragma unroll
        for (int i = 0; i < 4; ++i)
#pragma unroll
            for (int jj = 0; jj < 2; ++jj)
                acc[i][jj] = __builtin_amdgcn_mfma_f32_16x16x32_bf16(a[i], b[jj], acc[i][jj], 0, 0, 0);
    }
#pragma unroll
    for (int ks = 0; ks < 4; ++ks) {
        const int ck = ks * 4 + q;
        const int kk = ck * 8;
        bf16x8 a[4], b[2];
#pragma unroll
        for (int i = 0; i < 4; ++i)
            a[i] = *(const bf16x8*)&A[(wm * 64 + i * 16 + l15r) * 128 + (ck ^ l15r) * 8];
#pragma unroll
        for (int jj = 0; jj < 2; ++jj)
            b[jj] = *(const bf16x8*)&Wu1n[(wn * 32 + jj * 16 + l15) * 128 + kk];
#pragma unroll
        for (int i = 0; i < 4; ++i)
#pragma unroll
            for (int jj = 0; jj < 2; ++jj)
                acc[i][jj] = __builtin_amdgcn_mfma_f32_16x16x32_bf16(a[i], b[jj], acc[i][jj], 0, 0, 0);
    }
    __syncthreads();  // all A reads done; g loads drain here
    // park acc (bf16) into swizzled A — A is dead now
#pragma unroll
    for (int jj = 0; jj < 2; ++jj) {
        const int col = wn * 32 + jj * 16 + l15;
        const int cc = col >> 3, c7 = col & 7;
#pragma unroll
        for (int i = 0; i < 4; ++i)
#pragma unroll
            for (int r = 0; r < 4; ++r) {
                const int row = wm * 64 + i * 16 + q * 4 + r;
                A[row * 128 + (cc ^ (row & 15)) * 8 + c7] = f2bf(acc[i][jj][r]);
            }
    }
    __syncthreads();
    // vector epilogue: acc_seg + g (register) -> relu -> store
#pragma unroll
    for (int j = 0; j < 4; ++j) {
        const int task = j * 512 + t;
        const int row = task >> 4, sl = task & 15;
        const bf16x8 a8 = *(const bf16x8*)&A[row * 128 + (sl ^ (row & 15)) * 8];
        const bf16x8 g8 = g[j];
        uint4 pck;
        uint32_t parts[4];
#pragma unroll
        for (int hw = 0; hw < 4; ++hw) {
            float v0 = (float)a8[hw * 2] + (float)g8[hw * 2];
            float v1 = (float)a8[hw * 2 + 1] + (float)g8[hw * 2 + 1];
            v0 = v0 > 0.f ? v0 : 0.f;
            v1 = v1 > 0.f ? v1 : 0.f;
            parts[hw] = pack2(v0, v1);
        }
        pck.x = parts[0]; pck.y = parts[1]; pck.z = parts[2]; pck.w = parts[3];
        *(uint4*)(h_io + (size_t)(base + row) * H + sl * 8) = pck;
    }
}

// ---- FUSED final segsum + readout (R9 segsum) -----------------------------
__global__ __launch_bounds__(256, 4) void k_sr(
    const uint16_t* __restrict__ h, const int* __restrict__ row_ptr,
    const int* __restrict__ edge_slot, const uint16_t* __restrict__ Wr,
    const float* __restrict__ b_read, float* __restrict__ out) {
    __shared__ __align__(16) uint16_t S[128 * 136];
    __shared__ float col_lds[128];
    const int t = threadIdx.x;
    const int base = blockIdx.x * 128;
    const int qw = t >> 4, ql = t & 15;
    if (t < 128) col_lds[t] = 0.f;
    for (int s = 0; s < 8; ++s) {
        const int local = qw * 8 + s;
        const int a = base + local;
        float acc[8];
#pragma unroll
        for (int i = 0; i < 8; ++i) acc[i] = 0.f;
        if (a < N_ATOMS) {
            const int s0 = row_ptr[a], s1 = row_ptr[a + 1];
            int e[4];
#pragma unroll
            for (int i = 0; i < 4; ++i)
                e[i] = (s0 + i < s1) ? edge_slot[s0 + i] : -1;
            int p = s0;
            while (p < s1) {
                bf16x8 v[4];
                bool has[4];
#pragma unroll
                for (int i = 0; i < 4; ++i) {
                    has[i] = (p + i < s1);
                    if (has[i]) v[i] = *(const bf16x8*)(h + (size_t)e[i] * H + ql * 8);
                }
#pragma unroll
                for (int i = 0; i < 4; ++i) {
                    int np = p + 4 + i;
                    e[i] = (np < s1) ? edge_slot[np] : -1;
                }
#pragma unroll
                for (int i = 0; i < 4; ++i)
                    if (has[i]) {
#pragma unroll
                        for (int k = 0; k < 8; ++k) acc[k] += (float)v[i][k];
                    }
                p += 4;
            }
        }
        uint4 o;
        o.x = pack2(acc[0], acc[1]);
        o.y = pack2(acc[2], acc[3]);
        o.z = pack2(acc[4], acc[5]);
        o.w = pack2(acc[6], acc[7]);
        *(uint4*)&S[local * 136 + ql * 8] = o;
    }
    __syncthreads();
    const int w = t >> 6, lane = t & 63;
    const int wm = w >> 1, wn = w & 1;
    const int l15 = lane & 15, q = lane >> 4;
    f32x4 acc[4][4];
    const f32x4 z = {0.f, 0.f, 0.f, 0.f};
    for (int i = 0; i < 4; ++i)
        for (int jj = 0; jj < 4; ++jj) acc[i][jj] = z;
#pragma unroll
    for (int ks = 0; ks < 4; ++ks) {
        const int kk = ks * 32 + q * 8;
        bf16x8 a[4], b[4];
#pragma unroll
        for (int i = 0; i < 4; ++i)
            a[i] = *(const bf16x8*)&S[(wm * 64 + i * 16 + l15) * 136 + kk];
#pragma unroll
        for (int jj = 0; jj < 4; ++jj)
            b[jj] = *(const bf16x8*)&Wr[(wn * 64 + jj * 16 + l15) * KR + kk];
#pragma unroll
        for (int i = 0; i < 4; ++i)
#pragma unroll
            for (int jj = 0; jj < 4; ++jj)
                acc[i][jj] = __builtin_amdgcn_mfma_f32_16x16x32_bf16(a[i], b[jj], acc[i][jj], 0, 0, 0);
    }
#pragma unroll
    for (int jj = 0; jj < 4; ++jj) {
        const int col = wn * 64 + jj * 16 + l15;
        const float bias = b_read[col];
        float s = 0.f;
#pragma unroll
        for (int i = 0; i < 4; ++i)
#pragma unroll
            for (int r = 0; r < 4; ++r) {
                const int a_idx = base + wm * 64 + i * 16 + q * 4 + r;
                if (a_idx < N_ATOMS) {
                    float v = acc[i][jj][r] + bias;
                    s += (v > 0.f) ? v : 0.f;
                }
            }
        atomicAdd(&col_lds[col], s);
    }
    __syncthreads();
    if (t < 128) atomicAdd(&out[t], col_lds[t]);
}

// ---------------- launch ---------------------------------------------------
extern "C" void kernel_launch(void* const* d_in, const int* in_sizes, int n_in,
                              void* d_out, int out_size, void* d_ws, size_t ws_size,
                              hipStream_t stream) {
    (void)in_sizes; (void)n_in; (void)out_size; (void)ws_size;
    const float* atom   = (const float*)d_in[0];
    const float* bond   = (const float*)d_in[1];
    const int* edge_idx = (const int*)d_in[2];
    const float* W_init = (const float*)d_in[3];
    const float* b_init = (const float*)d_in[4];
    const float* W_upd  = (const float*)d_in[5];
    const float* b_upd  = (const float*)d_in[6];
    const float* W_read = (const float*)d_in[7];
    const float* b_read = (const float*)d_in[8];
    float* out = (float*)d_out;

    char* ws = (char*)d_ws;
    constexpr size_t SZ_H    = (size_t)N_EDGES * H * 2;            // 134217728
    constexpr size_t OFF_H   = 0;
    constexpr size_t OFF_P   = OFF_H + SZ_H;
    constexpr size_t OFF_G   = OFF_P + (size_t)N_ATOMS * H * 2;
    constexpr size_t OFF_WA  = OFF_G + (size_t)N_ATOMS * H * 2;
    constexpr size_t OFF_WB  = OFF_WA + (size_t)H * KI * 2;
    constexpr size_t OFF_WU0 = OFF_WB + (size_t)H * KB * 2;
    constexpr size_t OFF_WU1 = OFF_WU0 + (size_t)H * 128 * 2;
    constexpr size_t OFF_WU1N= OFF_WU1 + (size_t)H * 128 * 2;
    constexpr size_t OFF_WR  = OFF_WU1N + (size_t)H * 128 * 2;
    constexpr size_t OFF_CNT = OFF_WR + (size_t)H * KR * 2;
    constexpr size_t OFF_RP  = OFF_CNT + 200192;
    constexpr size_t OFF_NXT = OFF_RP + 200704;
    constexpr size_t OFF_ES  = OFF_NXT + 200192;
    constexpr size_t OFF_LS  = OFF_ES + (size_t)N_EDGES * 4;
    constexpr size_t OFF_PT  = OFF_LS + 512 * SCAN_NB * 4;
    constexpr size_t OFF_PO  = OFF_PT + 512;

    uint16_t* h     = (uint16_t*)(ws + OFF_H);
    uint16_t* P     = (uint16_t*)(ws + OFF_P);
    uint16_t* G     = (uint16_t*)(ws + OFF_G);
    uint16_t* Wa    = (uint16_t*)(ws + OFF_WA);
    uint16_t* Wb    = (uint16_t*)(ws + OFF_WB);
    uint16_t* Wu0   = (uint16_t*)(ws + OFF_WU0);
    uint16_t* Wu1   = (uint16_t*)(ws + OFF_WU1);
    uint16_t* Wu1n  = (uint16_t*)(ws + OFF_WU1N);
    uint16_t* Wr    = (uint16_t*)(ws + OFF_WR);
    int* counts     = (int*)(ws + OFF_CNT);
    int* row_ptr    = (int*)(ws + OFF_RP);
    int* nxt        = (int*)(ws + OFF_NXT);
    int* edge_slot  = (int*)(ws + OFF_ES);
    int* lscan      = (int*)(ws + OFF_LS);
    int* partials   = (int*)(ws + OFF_PT);
    int* poff       = (int*)(ws + OFF_PO);

    const int* srcv = edge_idx;
    const int* dstv = edge_idx + N_EDGES;

    hipMemsetAsync(counts, 0, N_ATOMS * sizeof(int), stream);
    hipMemsetAsync(d_out, 0, H * sizeof(float), stream);

    const int NW = H * KI + H * KB + 3 * H * 128 + H * KR;  // 90112
    k_weights<<<(NW + 255) / 256, 256, 0, stream>>>(
        W_init, W_upd, W_read, Wa, Wb, Wu0, Wu1, Wu1n, Wr);
    k_hist<<<(N_EDGES + 255) / 256, 256, 0, stream>>>(dstv, counts);
    k_scan1<<<SCAN_NB, 512, 0, stream>>>(counts, lscan, partials);
    k_scan2<<<1, 128, 0, stream>>>(partials, poff);
    k_scan3<<<SCAN_NB, 512, 0, stream>>>(lscan, poff, row_ptr, nxt);
    k_scatter<<<(N_EDGES + 255) / 256, 256, 0, stream>>>(dstv, nxt, edge_slot);

    k_atom_gemm<<<(N_ATOMS + 127) / 128, 256, 0, stream>>>(atom, Wa, P);
    k_edge_init<<<N_EDGES / 128, 256, 0, stream>>>(bond, srcv, Wb, P, b_init, h);

    for (int d = 0; d < DEPTH; ++d) {
        k_sg<<<(N_ATOMS + 127) / 128, 256, 0, stream>>>(h, row_ptr, edge_slot, Wu1, b_upd, G);
        k_update<<<N_EDGES / 128, 512, 0, stream>>>(h, G, srcv, Wu0, Wu1n);
    }
    k_sr<<<(N_ATOMS + 127) / 128, 256, 0, stream>>>(h, row_ptr, edge_slot, Wr, b_read, out);
}